// Round 5
// baseline (249.643 us; speedup 1.0000x reference)
//
#include <hip/hip_runtime.h>
#include <stdint.h>

#define E_N 16
#define HID 2048
#define INTER_D 4096
#define NPAIR 2048
#define NTOK 1024
#define CAP 256

typedef __attribute__((ext_vector_type(8))) short bf16x8;
typedef __attribute__((ext_vector_type(4))) float f32x4;

static __device__ __forceinline__ unsigned short f2bf(float f) {
  union { float f; unsigned int u; } x; x.f = f;
  unsigned int r = x.u + 0x7fffu + ((x.u >> 16) & 1u);
  return (unsigned short)(r >> 16);
}

// ---------------- routing: per-expert pair lists ----------------
__global__ void route_kernel(const int* __restrict__ idx, int* __restrict__ counts,
                             int* __restrict__ gidlist) {
  __shared__ int cnt[E_N];
  const int tid = threadIdx.x;
  if (tid < E_N) cnt[tid] = 0;
  for (int j = tid; j < E_N * CAP; j += 256) gidlist[j] = 0;  // pad with valid gid 0
  __syncthreads();
  for (int p = tid; p < NPAIR; p += 256) {
    int e = idx[p] & 15;
    int pos = atomicAdd(&cnt[e], 1);
    if (pos < CAP) gidlist[e * CAP + pos] = p;
  }
  __syncthreads();
  if (tid < E_N) counts[tid] = (cnt[tid] < CAP) ? cnt[tid] : CAP;
}

// ---------------- tokens fp32 -> bf16 ----------------
__global__ void prep_a_kernel(const float* __restrict__ tok, unsigned short* __restrict__ A1) {
  const int i = (blockIdx.x * 256 + threadIdx.x) * 4;
  const float4 v = *reinterpret_cast<const float4*>(tok + i);
  ushort4 o;
  o.x = f2bf(v.x); o.y = f2bf(v.y); o.z = f2bf(v.z); o.w = f2bf(v.w);
  *reinterpret_cast<ushort4*>(A1 + i) = o;
}

// ---------------- grouped GEMM (single barrier per K-step) ----------------
// MODE 0: h[gid] = bf16(relu(A1[tok(gid)] @ w1[e] + b1[e]))   (KDIM=2048, NDIM=4096)
// MODE 1: out[tok] += tw[gid] * (h[gid] @ w2[e] + b2[e])      (KDIM=4096, NDIM=2048)
// BM=256, BN=128, BK=64, 16 waves (4M x 4N), per-wave 64x32.
// A triple-buffered (3x32K), B LDS double-buffered (2x16K) -> ONE s_barrier per step.
// Steady state: enter step t with {B(t+1) regs, A(t+1) lds-loads} in flight (4 ops);
// issue {B(t+2), A(t+2)}; writeB(t+1) (compiler in-order vmcnt retires B(t+1));
// compute(t); lgkmcnt(0); vmcnt(4) (retires A(t+1), keeps 4 newest in flight); barrier.
template <int KDIM, int NDIM, int MODE>
__global__ __launch_bounds__(1024, 4) void moe_gemm_kernel(
    const unsigned short* __restrict__ Asrc,  // bf16 rows, stride KDIM
    const float* __restrict__ W,              // [E][KDIM][NDIM] fp32
    const float* __restrict__ bias,           // [E][NDIM]
    const float* __restrict__ tw,             // [NPAIR] (MODE 1)
    const int* __restrict__ counts,
    const int* __restrict__ gidlist,
    unsigned short* __restrict__ Hout,        // MODE 0
    float* __restrict__ Oout) {               // MODE 1 (atomic)
  const int e = blockIdx.y;
  const int ne = counts[e];
  if (ne <= 0) return;
  const int n0 = blockIdx.x * 128;
  const int tid = threadIdx.x;
  const int lane = tid & 63;
  const int wv = tid >> 6;   // 0..15
  const int wm = wv >> 2;    // M group of 64 rows
  const int wn = wv & 3;     // N group of 32 cols

  extern __shared__ char smem[];
  char* Ab0 = smem;              // 3 x 32 KiB A bufs (bf16 [256][64], source-swizzled)
  char* Ab1 = smem + 32768;
  char* Ab2 = smem + 65536;
  char* Bs0 = smem + 98304;      // 2 x 16 KiB B bufs (bf16 [128 n][64 k], XOR-swizzled)
  char* Bs1 = smem + 114688;
  __shared__ int sgid[CAP];
  if (tid < CAP) sgid[tid] = gidlist[e * CAP + tid];
  __syncthreads();

  // ---- A staging (global_load_lds, dest linear, source pre-swizzled) ----
  const int c16 = (lane & 7) ^ ((lane >> 3) & 7);  // inverse swizzle on source column
  const unsigned short* arp[2];
#pragma unroll
  for (int i = 0; i < 2; ++i) {
    const int row = (wv * 2 + i) * 8 + (lane >> 3);
    const int gid = sgid[row];
    const long arow = (MODE == 0) ? (gid >> 1) : gid;
    arp[i] = Asrc + arow * (long)KDIM + c16 * 8;
  }

  // ---- B staging: thread loads 2 rows(k) x 4 cols(n) fp32, transposes, packs bf16 ----
  const int bn4 = (tid & 31) * 4;
  const int bk2 = (tid >> 5) * 2;
  const float* wbase = W + (long)e * KDIM * NDIM + n0 + bn4;
  int bbyte[4];
#pragma unroll
  for (int c = 0; c < 4; ++c)
    bbyte[c] = (((bn4 + c) * 128) + bk2 * 2) ^ ((tid & 7) << 4);

  auto loadB = [&](int t, float4& r0, float4& r1) {
    const float* p = wbase + (long)(t * 64 + bk2) * NDIM;
    r0 = *reinterpret_cast<const float4*>(p);
    r1 = *reinterpret_cast<const float4*>(p + NDIM);
  };
  auto writeB = [&](char* Bb, const float4& r0, const float4& r1) {
    const float a0[4] = {r0.x, r0.y, r0.z, r0.w};
    const float a1[4] = {r1.x, r1.y, r1.z, r1.w};
#pragma unroll
    for (int c = 0; c < 4; ++c) {
      unsigned int u = (unsigned int)f2bf(a0[c]) | ((unsigned int)f2bf(a1[c]) << 16);
      *reinterpret_cast<unsigned int*>(Bb + bbyte[c]) = u;
    }
  };
  auto stageA = [&](int t, char* buf) {
#pragma unroll
    for (int i = 0; i < 2; ++i) {
      char* dst = buf + (wv * 2 + i) * 1024;  // wave-uniform base; HW adds lane*16
      __builtin_amdgcn_global_load_lds(
          (const __attribute__((address_space(1))) void*)(arp[i] + t * 64),
          (__attribute__((address_space(3))) void*)dst, 16, 0, 0);
    }
  };

  // ---- fragment LDS byte offsets ----
  const int rl = lane & 15;
  const int kg = lane >> 4;  // 0..3
  int abyte[4][2], bbyteF[2][2];
#pragma unroll
  for (int mf = 0; mf < 4; ++mf) {
    const int row = wm * 64 + mf * 16 + rl;
#pragma unroll
    for (int ks = 0; ks < 2; ++ks) {
      const int unit = (ks * 4 + kg) ^ (lane & 7);
      abyte[mf][ks] = row * 128 + unit * 16;
    }
  }
#pragma unroll
  for (int nf = 0; nf < 2; ++nf) {
    const int n = wn * 32 + nf * 16 + rl;
#pragma unroll
    for (int ks = 0; ks < 2; ++ks)
      bbyteF[nf][ks] = ((n * 128) + (ks * 32 + kg * 8) * 2) ^ (((n >> 2) & 7) << 4);
  }

  f32x4 acc[4][2];
#pragma unroll
  for (int mf = 0; mf < 4; ++mf)
#pragma unroll
    for (int nf = 0; nf < 2; ++nf) acc[mf][nf] = (f32x4)(0.0f);

  const bool mact = (wm * 64) < ne;  // wave-level skip of all-padding rows
  constexpr int NK = KDIM / 64;      // 32 or 64

  auto compute = [&](const char* Ab, const char* Bb) {
#pragma unroll
    for (int ks = 0; ks < 2; ++ks) {
      bf16x8 af[4], bfr[2];
#pragma unroll
      for (int mf = 0; mf < 4; ++mf)
        af[mf] = *reinterpret_cast<const bf16x8*>(Ab + abyte[mf][ks]);
#pragma unroll
      for (int nf = 0; nf < 2; ++nf)
        bfr[nf] = *reinterpret_cast<const bf16x8*>(Bb + bbyteF[nf][ks]);
#pragma unroll
      for (int mf = 0; mf < 4; ++mf)
#pragma unroll
        for (int nf = 0; nf < 2; ++nf)
          acc[mf][nf] = __builtin_amdgcn_mfma_f32_16x16x32_bf16(
              af[mf], bfr[nf], acc[mf][nf], 0, 0, 0);
    }
  };

  // 2 statically-named B register sets (rule #20): tile t -> set (t & 1).
  float4 s00, s01, s10, s11;

#define LGKM0 asm volatile("s_waitcnt lgkmcnt(0)" ::: "memory")
#define VM4   asm volatile("s_waitcnt vmcnt(4)" ::: "memory")
#define BARRIER asm volatile("s_barrier" ::: "memory")
  // Single-barrier pipeline step for tile T.
#define FSTEP(T, AW, AR, BW, BR, W0, W1, L0, L1)  \
  {                                               \
    loadB((T) + 2, L0, L1);                       \
    stageA((T) + 2, AW);                          \
    writeB(BW, W0, W1);                           \
    if (mact) compute(AR, BR);                    \
    LGKM0;                                        \
    VM4;                                          \
    BARRIER;                                      \
  }

  // ---- prologue ----
  loadB(0, s00, s01); stageA(0, Ab0);
  loadB(1, s10, s11); stageA(1, Ab1);
  writeB(Bs0, s00, s01);   // compiler in-order vmcnt retires B(0)
  LGKM0;
  VM4;                     // retires A(0); keeps {B(1), A(1)} in flight
  BARRIER;

  // ---- main loop: full steps t = 0 .. NK-3, unrolled x6 (LCM of Ax3, Bx2) ----
  for (int tb = 0; tb + 6 <= NK - 2; tb += 6) {
    FSTEP(tb + 0, Ab2, Ab0, Bs1, Bs0, s10, s11, s00, s01);
    FSTEP(tb + 1, Ab0, Ab1, Bs0, Bs1, s00, s01, s10, s11);
    FSTEP(tb + 2, Ab1, Ab2, Bs1, Bs0, s10, s11, s00, s01);
    FSTEP(tb + 3, Ab2, Ab0, Bs0, Bs1, s00, s01, s10, s11);
    FSTEP(tb + 4, Ab0, Ab1, Bs1, Bs0, s10, s11, s00, s01);
    FSTEP(tb + 5, Ab1, Ab2, Bs0, Bs1, s00, s01, s10, s11);
  }
  if constexpr ((NK - 2) % 6 == 2) {  // KDIM=4096: peel t = NK-4 (≡0 mod 6), NK-3 (≡1)
    FSTEP(NK - 4, Ab2, Ab0, Bs1, Bs0, s10, s11, s00, s01);
    FSTEP(NK - 3, Ab0, Ab1, Bs0, Bs1, s00, s01, s10, s11);
  }

  // ---- tail t = NK-2: no new loads; drain ----
  {
    char* const Abufs[3] = {Ab0, Ab1, Ab2};
    writeB(Bs1, s10, s11);                       // B(NK-1): set (NK-3)&1 = 1 for NK in {32,64}
    if (mact) compute(Abufs[(NK - 2) % 3], Bs0); // (NK-2) even -> Bs0
    LGKM0;
    asm volatile("s_waitcnt vmcnt(0)" ::: "memory");  // A(NK-1) landed
    BARRIER;
    // ---- tail t = NK-1 ----
    if (mact) compute(Abufs[(NK - 1) % 3], Bs1);
  }
#undef FSTEP
#undef LGKM0
#undef VM4
#undef BARRIER

  // ---- epilogue ----
  if (mact) {
    const int rg = (lane >> 4) * 4;
    float bc[2];
#pragma unroll
    for (int nf = 0; nf < 2; ++nf)
      bc[nf] = bias[(long)e * NDIM + n0 + wn * 32 + nf * 16 + rl];
#pragma unroll
    for (int mf = 0; mf < 4; ++mf) {
#pragma unroll
      for (int r = 0; r < 4; ++r) {
        const int row = wm * 64 + mf * 16 + rg + r;
        if (row < ne) {
          const int gid = sgid[row];
#pragma unroll
          for (int nf = 0; nf < 2; ++nf) {
            const int col = n0 + wn * 32 + nf * 16 + rl;
            float v = acc[mf][nf][r] + bc[nf];
            if constexpr (MODE == 0) {
              v = fmaxf(v, 0.0f);
              Hout[(long)gid * NDIM + col] = f2bf(v);
            } else {
              v *= tw[gid];
              atomicAdd(Oout + (long)(gid >> 1) * NDIM + col, v);
            }
          }
        }
      }
    }
  }
}

extern "C" void kernel_launch(void* const* d_in, const int* in_sizes, int n_in,
                              void* d_out, int out_size, void* d_ws, size_t ws_size,
                              hipStream_t stream) {
  const float* tokens = (const float*)d_in[0];
  const int* idx      = (const int*)d_in[1];
  const float* tw     = (const float*)d_in[2];
  const float* w1     = (const float*)d_in[3];
  const float* b1     = (const float*)d_in[4];
  const float* w2     = (const float*)d_in[5];
  const float* b2     = (const float*)d_in[6];
  float* out = (float*)d_out;

  char* ws = (char*)d_ws;
  int* counts  = (int*)ws;
  int* gidlist = (int*)(ws + 1024);
  unsigned short* A1   = (unsigned short*)(ws + 32768);
  unsigned short* hbuf = (unsigned short*)(ws + 32768 + (size_t)NTOK * HID * 2);

  hipMemsetAsync(out, 0, (size_t)NTOK * HID * sizeof(float), stream);
  route_kernel<<<1, 256, 0, stream>>>(idx, counts, gidlist);
  prep_a_kernel<<<(NTOK * HID / 4) / 256, 256, 0, stream>>>(tokens, A1);

  hipFuncSetAttribute((const void*)moe_gemm_kernel<HID, INTER_D, 0>,
                      hipFuncAttributeMaxDynamicSharedMemorySize, 131072);
  hipFuncSetAttribute((const void*)moe_gemm_kernel<INTER_D, HID, 1>,
                      hipFuncAttributeMaxDynamicSharedMemorySize, 131072);

  dim3 g1(INTER_D / 128, E_N);  // 32 x 16
  moe_gemm_kernel<HID, INTER_D, 0><<<g1, 1024, 131072, stream>>>(
      A1, w1, b1, nullptr, counts, gidlist, hbuf, nullptr);
  dim3 g2(HID / 128, E_N);      // 16 x 16
  moe_gemm_kernel<INTER_D, HID, 1><<<g2, 1024, 131072, stream>>>(
      hbuf, w2, b2, tw, counts, gidlist, nullptr, out);
}